// Round 3
// baseline (1077.555 us; speedup 1.0000x reference)
//
#include <hip/hip_runtime.h>
#include <stdint.h>

#define NN 2048
#define TT 10
#define KST 5
#define BK 64
#define NKT2 (NN / BK)   // 32 K-tiles of 64

typedef float f32x4 __attribute__((ext_vector_type(4)));
typedef __bf16 bf16x8 __attribute__((ext_vector_type(8)));
typedef unsigned short u16x8 __attribute__((ext_vector_type(8)));

using as3_void = __attribute__((address_space(3))) void;
using as1_const_void = const __attribute__((address_space(1))) void;

__device__ __forceinline__ unsigned short f2bf_bits(float f) {
    unsigned u = __builtin_bit_cast(unsigned, f);
    unsigned r = u + 0x7FFFu + ((u >> 16) & 1u);   // RNE
    return (unsigned short)(r >> 16);
}
__device__ __forceinline__ float bf2f(unsigned short b) {
    return __builtin_bit_cast(float, ((unsigned)b) << 16);
}

// ---------------- deg[t][i] = sum_j x[i][t][j] + 1e-8 ----------------
__global__ __launch_bounds__(256) void deg_kernel(const float* __restrict__ x,
                                                  float* __restrict__ deg) {
    const int i = blockIdx.x;
    const int t = blockIdx.y;
    const int tid = threadIdx.x;
    const float4* r4 = (const float4*)(x + ((size_t)i * TT + t) * NN);
    float4 a = r4[tid];
    float4 b = r4[tid + 256];
    float s = a.x + a.y + a.z + a.w + b.x + b.y + b.z + b.w;
    #pragma unroll
    for (int m = 32; m >= 1; m >>= 1) s += __shfl_xor(s, m, 64);
    __shared__ float red[4];
    if ((tid & 63) == 0) red[tid >> 6] = s;
    __syncthreads();
    if (tid == 0) deg[(size_t)t * NN + i] = red[0] + red[1] + red[2] + red[3] + 1e-8f;
}

// ---- GnT[tl][n][k] = bf16(Gn[k][n]) AND P1[tl][k][n] = bf16(w0*Gn + (1-w0)I) ----
__global__ __launch_bounds__(256) void gnt_init_kernel(const float* __restrict__ x,
                                                       const float* __restrict__ deg,
                                                       const float* __restrict__ w,
                                                       unsigned short* __restrict__ gnt,
                                                       unsigned short* __restrict__ p1,
                                                       int t0) {
    const int tl = blockIdx.z;
    const int t  = t0 + tl;
    float w0 = w[t * KST + 0];
    w0 = fminf(fmaxf(w0, 0.0f), 1.0f);
    const float om = 1.0f - w0;
    const int n0 = blockIdx.x * 64;
    const int k0 = blockIdx.y * 64;
    __shared__ float tile[64][65];
    const int tx = threadIdx.x & 63;
    const int ty = threadIdx.x >> 6;
    unsigned short* p1dst = p1 + (size_t)tl * NN * NN;
    #pragma unroll
    for (int p = 0; p < 16; ++p) {
        int kr = p * 4 + ty;
        float rd = 1.0f / deg[(size_t)t * NN + k0 + kr];
        float v = x[(((size_t)(k0 + kr)) * TT + t) * NN + n0 + tx] * rd;
        tile[kr][tx] = v;
        float pv = w0 * v + ((k0 + kr) == (n0 + tx) ? om : 0.0f);
        p1dst[(size_t)(k0 + kr) * NN + n0 + tx] = f2bf_bits(pv);
    }
    __syncthreads();
    unsigned short* dst = gnt + (size_t)tl * NN * NN;
    #pragma unroll
    for (int p = 0; p < 16; ++p) {
        int nr = p * 4 + ty;
        dst[(size_t)(n0 + nr) * NN + k0 + tx] = f2bf_bits(tile[tx][nr]);
    }
}

// ==========================================================================
// 256x256 tile, BK=64, 8 waves (2M x 4N), 128KB double-buffered LDS.
// R2 schedule (retry — R2 bench was an infra failure, schedule re-audited):
// 3 phases per K-tile, ONE barrier per phase (at head, after the vmcnt
// wait), all 4 half-tile stages clumped into P0/P1 so every wait targets
// loads issued a full K-tile (3-4 phases) earlier:
//   P0: wait vmcnt(4); bar; read A0->af, B0->bf0; stage A0',B0'; 16 MFMA
//   P1: wait vmcnt(6); bar; read B1->bf1;          stage B1',A1'; 16 MFMA
//   P2: wait vmcnt(8); bar; read A1->af;                          32 MFMA
// bf0/bf1 retained in regs across the tile -> no LDS re-read of B0.
// WAR audit: every LDS half written at phase P was last read >=2 barriers
// earlier by all waves; reads complete before the intervening barrier
// because the MFMAs consuming them precede it in program order.
// ==========================================================================
#define FENCE __asm__ volatile("" ::: "memory")

#define MFMA_PHASE(PA, PB, BARR)                                                  \
  do {                                                                            \
    _Pragma("unroll")                                                             \
    for (int f_ = 0; f_ < 4; ++f_) {                                              \
      _Pragma("unroll")                                                           \
      for (int g_ = 0; g_ < 2; ++g_) {                                            \
        acc[(PA)*4 + f_][(PB)*2 + g_] = __builtin_amdgcn_mfma_f32_16x16x32_bf16(  \
            af[f_][0], BARR[g_][0], acc[(PA)*4 + f_][(PB)*2 + g_], 0, 0, 0);      \
        acc[(PA)*4 + f_][(PB)*2 + g_] = __builtin_amdgcn_mfma_f32_16x16x32_bf16(  \
            af[f_][1], BARR[g_][1], acc[(PA)*4 + f_][(PB)*2 + g_], 0, 0, 0);      \
      }                                                                           \
    }                                                                             \
  } while (0)

__global__ __launch_bounds__(512, 2) void gemm_step256(
        const unsigned short* __restrict__ Pprev,
        const unsigned short* __restrict__ gnt,
        const float* __restrict__ w,
        unsigned short* __restrict__ Pnext,
        int t0, int kstep) {
    extern __shared__ char smem[];

    // bijective XCD swizzle (m204) + 2x2 supertiles (4MB strip set per XCD L2)
    const int nwg  = (int)gridDim.x;
    const int flat = (int)blockIdx.x;
    const int xcd  = flat & 7;
    const int q    = nwg >> 3, r = nwg & 7;
    const int wgid = (xcd < r ? xcd * (q + 1) : r * (q + 1) + (xcd - r) * q) + (flat >> 3);
    const int tl   = wgid >> 6;            // 64 tiles per time-slice
    const int s    = wgid & 63;
    const int g4   = s >> 2, w4 = s & 3;
    const int tm   = ((g4 >> 2) << 1) | (w4 >> 1);
    const int tn   = ((g4 & 3) << 1) | (w4 & 1);
    const int t    = t0 + tl;

    const int tid  = threadIdx.x;
    const int lane = tid & 63;
    const int wv   = tid >> 6;        // 0..7
    const int wm   = wv >> 2;         // 0..1 (M split)
    const int wn   = wv & 3;          // 0..3 (N split)
    const int lr   = lane & 15;
    const int quad = lane >> 4;
    const int swz  = lr & 7;          // read-side row swizzle key

    const unsigned short* Ab = Pprev + (size_t)tl * NN * NN;
    const unsigned short* Bb = gnt   + (size_t)tl * NN * NN;

    // --- staging source addresses (pre-swizzled k-slot, rule 21) ---
    const int srow  = lane >> 3;               // row low bits within 8-row stripe
    const int sslot = (lane & 7) ^ srow;       // inverse-swizzled 16B k-slot
    const unsigned short* pa[2][2];
    const unsigned short* pb[2][2];
    #pragma unroll
    for (int h = 0; h < 2; ++h)
        #pragma unroll
        for (int l = 0; l < 2; ++l) {
            const int rA = tm * 256 + h * 128 + l * 64 + wv * 8 + srow;
            const int rB = tn * 256 + h * 128 + l * 64 + wv * 8 + srow;
            pa[h][l] = Ab + (size_t)rA * NN + sslot * 8;
            pb[h][l] = Bb + (size_t)rB * NN + sslot * 8;
        }

    // LDS map: A half h of buf b at b*65536 + h*16384 ; B at +32768.
    // half = [128 rows][64 k] bf16, 128B rows, linear (global_load_lds dest).
    auto stageA = [&](int kt, int b, int h) {
        #pragma unroll
        for (int l = 0; l < 2; ++l)
            __builtin_amdgcn_global_load_lds(
                (as1_const_void*)(pa[h][l] + kt * BK),
                (as3_void*)(smem + b * 65536 + h * 16384 + l * 8192 + wv * 1024),
                16, 0, 0);
    };
    auto stageB = [&](int kt, int b, int h) {
        #pragma unroll
        for (int l = 0; l < 2; ++l)
            __builtin_amdgcn_global_load_lds(
                (as1_const_void*)(pb[h][l] + kt * BK),
                (as3_void*)(smem + b * 65536 + 32768 + h * 16384 + l * 8192 + wv * 1024),
                16, 0, 0);
    };

    // --- fragment loads (swizzled ds_read_b128, conflict-free) ---
    bf16x8 af[4][2];     // 4 m-frags x 2 k-slabs of current A-half
    bf16x8 bf0[2][2];    // B half0 frags (retained across the K-tile)
    bf16x8 bf1[2][2];    // B half1 frags
    const int sA = ((quad)     ^ swz) * 16;    // k-slab 0 slot byte
    const int sB = ((quad + 4) ^ swz) * 16;    // k-slab 1 slot byte
    auto lda = [&](int b, int half) {
        const char* base = smem + b * 65536 + half * 16384 + (wm * 64 + lr) * 128;
        #pragma unroll
        for (int f = 0; f < 4; ++f) {
            af[f][0] = *(const bf16x8*)(base + f * 2048 + sA);
            af[f][1] = *(const bf16x8*)(base + f * 2048 + sB);
        }
    };
    auto ldb = [&](int b, int half, bf16x8 (&dst)[2][2]) {
        const char* base = smem + b * 65536 + 32768 + half * 16384 + (wn * 32 + lr) * 128;
        #pragma unroll
        for (int g = 0; g < 2; ++g) {
            dst[g][0] = *(const bf16x8*)(base + g * 2048 + sA);
            dst[g][1] = *(const bf16x8*)(base + g * 2048 + sB);
        }
    };

    f32x4 acc[8][4];
    #pragma unroll
    for (int i = 0; i < 8; ++i)
        #pragma unroll
        for (int j = 0; j < 4; ++j)
            acc[i][j] = (f32x4){0.0f, 0.0f, 0.0f, 0.0f};

    // prologue: stage tile 0 into buf 0 in issue order A0,B0,B1,A1
    stageA(0, 0, 0);
    stageB(0, 0, 0);
    stageB(0, 0, 1);
    stageA(0, 0, 1);

    for (int kt = 0; kt < NKT2 - 1; ++kt) {
        const int buf  = kt & 1;
        const int nbuf = buf ^ 1;
        // P0: needs A0,B0 (oldest 4 loads) -> vmcnt(4); issued a full tile ago
        FENCE; __builtin_amdgcn_s_waitcnt(0xF74); __builtin_amdgcn_s_barrier(); FENCE;
        lda(buf, 0);
        ldb(buf, 0, bf0);
        stageA(kt + 1, nbuf, 0);
        stageB(kt + 1, nbuf, 0);
        __builtin_amdgcn_s_setprio(1);
        MFMA_PHASE(0, 0, bf0);
        __builtin_amdgcn_s_setprio(0);
        // P1: needs B1 (next-oldest 2) -> vmcnt(6)
        FENCE; __builtin_amdgcn_s_waitcnt(0xF76); __builtin_amdgcn_s_barrier(); FENCE;
        ldb(buf, 1, bf1);
        stageB(kt + 1, nbuf, 1);
        stageA(kt + 1, nbuf, 1);
        __builtin_amdgcn_s_setprio(1);
        MFMA_PHASE(0, 1, bf1);
        __builtin_amdgcn_s_setprio(0);
        // P2: needs A1 -> vmcnt(8); then 32 MFMA (both B halves from regs)
        FENCE; __builtin_amdgcn_s_waitcnt(0xF78); __builtin_amdgcn_s_barrier(); FENCE;
        lda(buf, 1);
        __builtin_amdgcn_s_setprio(1);
        MFMA_PHASE(1, 1, bf1);
        MFMA_PHASE(1, 0, bf0);
        __builtin_amdgcn_s_setprio(0);
    }

    {   // epilogue K-tile (no staging): waits tighten 4 -> 2 -> 0
        const int buf = (NKT2 - 1) & 1;
        FENCE; __builtin_amdgcn_s_waitcnt(0xF74); __builtin_amdgcn_s_barrier(); FENCE;
        lda(buf, 0);
        ldb(buf, 0, bf0);
        __builtin_amdgcn_s_setprio(1);
        MFMA_PHASE(0, 0, bf0);
        __builtin_amdgcn_s_setprio(0);
        FENCE; __builtin_amdgcn_s_waitcnt(0xF72); __builtin_amdgcn_s_barrier(); FENCE;
        ldb(buf, 1, bf1);
        __builtin_amdgcn_s_setprio(1);
        MFMA_PHASE(0, 1, bf1);
        __builtin_amdgcn_s_setprio(0);
        FENCE; __builtin_amdgcn_s_waitcnt(0xF70); __builtin_amdgcn_s_barrier(); FENCE;
        lda(buf, 1);
        __builtin_amdgcn_s_setprio(1);
        MFMA_PHASE(1, 1, bf1);
        MFMA_PHASE(1, 0, bf0);
        __builtin_amdgcn_s_setprio(0);
    }

    // epilogue: P_next = wk*acc + (1-wk)*I, bf16
    float wk = w[t * KST + kstep];
    wk = fminf(fmaxf(wk, 0.0f), 1.0f);
    const float om = 1.0f - wk;
    unsigned short* __restrict__ Pn = Pnext + (size_t)tl * NN * NN;
    #pragma unroll
    for (int F = 0; F < 8; ++F) {
        const int mrow0 = tm * 256 + (F >> 2) * 128 + wm * 64 + (F & 3) * 16 + quad * 4;
        #pragma unroll
        for (int v = 0; v < 4; ++v) {
            const int m = mrow0 + v;
            const size_t mb = (size_t)m * NN;
            #pragma unroll
            for (int G = 0; G < 4; ++G) {
                const int n = tn * 256 + (G >> 1) * 128 + wn * 32 + (G & 1) * 16 + lr;
                float val = wk * acc[F][G][v] + (m == n ? om : 0.0f);
                Pn[mb + n] = f2bf_bits(val);
            }
        }
    }
}

// ---- out[m][t][:] = LayerNorm( sum_k P_k[m][:] ), P_k bf16 ----
__global__ __launch_bounds__(256) void ln_kernel(const unsigned short* __restrict__ Pall,
                                                 const float* __restrict__ gamma,
                                                 const float* __restrict__ beta,
                                                 float* __restrict__ out,
                                                 int t0, size_t strideK) {
    const int m  = blockIdx.x;
    const int tl = blockIdx.y;
    const int t  = t0 + tl;
    const int tid = threadIdx.x;
    const int j = tid * 8;

    const size_t rbase = (size_t)tl * NN * NN + (size_t)m * NN + j;
    float v[8] = {0, 0, 0, 0, 0, 0, 0, 0};
    #pragma unroll
    for (int k = 0; k < KST; ++k) {
        u16x8 pv = *(const u16x8*)(Pall + (size_t)k * strideK + rbase);
        #pragma unroll
        for (int e = 0; e < 8; ++e) v[e] += bf2f(pv[e]);
    }

    float s = 0.0f;
    #pragma unroll
    for (int e = 0; e < 8; ++e) s += v[e];
    #pragma unroll
    for (int mm = 32; mm >= 1; mm >>= 1) s += __shfl_xor(s, mm, 64);
    __shared__ float red[4];
    if ((tid & 63) == 0) red[tid >> 6] = s;
    __syncthreads();
    const float mu = (red[0] + red[1] + red[2] + red[3]) * (1.0f / NN);

    float q = 0.0f;
    float dx[8];
    #pragma unroll
    for (int e = 0; e < 8; ++e) { dx[e] = v[e] - mu; q += dx[e] * dx[e]; }
    __syncthreads();
    #pragma unroll
    for (int mm = 32; mm >= 1; mm >>= 1) q += __shfl_xor(q, mm, 64);
    if ((tid & 63) == 0) red[tid >> 6] = q;
    __syncthreads();
    const float var = (red[0] + red[1] + red[2] + red[3]) * (1.0f / NN);
    const float sc = rsqrtf(var + 1e-5f);

    float4 g0 = *(const float4*)(gamma + j);
    float4 g1 = *(const float4*)(gamma + j + 4);
    float4 b0 = *(const float4*)(beta + j);
    float4 b1 = *(const float4*)(beta + j + 4);
    const size_t ob = ((size_t)m * TT + t) * NN + j;
    float4 o0, o1;
    o0.x = dx[0] * sc * g0.x + b0.x;  o0.y = dx[1] * sc * g0.y + b0.y;
    o0.z = dx[2] * sc * g0.z + b0.z;  o0.w = dx[3] * sc * g0.w + b0.w;
    o1.x = dx[4] * sc * g1.x + b1.x;  o1.y = dx[5] * sc * g1.y + b1.y;
    o1.z = dx[6] * sc * g1.z + b1.z;  o1.w = dx[7] * sc * g1.w + b1.w;
    *(float4*)(out + ob)     = o0;
    *(float4*)(out + ob + 4) = o1;
}

extern "C" void kernel_launch(void* const* d_in, const int* in_sizes, int n_in,
                              void* d_out, int out_size, void* d_ws, size_t ws_size,
                              hipStream_t stream) {
    (void)in_sizes; (void)n_in; (void)out_size;
    const float* x     = (const float*)d_in[0];
    const float* w     = (const float*)d_in[1];
    const float* gamma = (const float*)d_in[2];
    const float* beta  = (const float*)d_in[3];
    float* out = (float*)d_out;

    static bool attr_done = false;
    if (!attr_done) {
        (void)hipFuncSetAttribute((const void*)gemm_step256,
                                  hipFuncAttributeMaxDynamicSharedMemorySize, 131072);
        attr_done = true;
    }

    char* ws = (char*)d_ws;
    float* deg = (float*)ws;
    size_t off = ((size_t)TT * NN * sizeof(float) + 255) & ~(size_t)255;
    const size_t per_t = (size_t)NN * NN * sizeof(unsigned short);   // 8 MB
    size_t avail = ws_size > off ? ws_size - off : 0;
    int TB = (int)(avail / ((1 + KST) * per_t));
    if (TB < 1) TB = 1;
    if (TB > TT) TB = TT;
    unsigned short* gnt  = (unsigned short*)(ws + off);
    unsigned short* Pall = gnt + (size_t)TB * NN * NN;
    const size_t strideK = (size_t)TB * NN * NN;

    deg_kernel<<<dim3(NN, TT), 256, 0, stream>>>(x, deg);

    for (int t0 = 0; t0 < TT; t0 += TB) {
        const int tb = (TT - t0) < TB ? (TT - t0) : TB;
        gnt_init_kernel<<<dim3(32, 32, tb), 256, 0, stream>>>(x, deg, w, gnt, Pall, t0);
        for (int k = 2; k <= KST; ++k) {
            const unsigned short* Pp = Pall + (size_t)(k - 2) * strideK;
            unsigned short*       Pn = Pall + (size_t)(k - 1) * strideK;
            gemm_step256<<<dim3(64 * tb), 512, 131072, stream>>>(Pp, gnt, w, Pn, t0, k - 1);
        }
        ln_kernel<<<dim3(NN, tb), 256, 0, stream>>>(Pall, gamma, beta, out, t0, strideK);
    }
}

// Round 4
// 1051.338 us; speedup vs baseline: 1.0249x; 1.0249x over previous
//
#include <hip/hip_runtime.h>
#include <stdint.h>

#define NN 2048
#define TT 10
#define KST 5
#define BK 64
#define NKT2 (NN / BK)   // 32 K-tiles of 64

typedef float f32x4 __attribute__((ext_vector_type(4)));
typedef __bf16 bf16x8 __attribute__((ext_vector_type(8)));
typedef unsigned short u16x8 __attribute__((ext_vector_type(8)));

using as3_void = __attribute__((address_space(3))) void;
using as1_const_void = const __attribute__((address_space(1))) void;

__device__ __forceinline__ unsigned short f2bf_bits(float f) {
    unsigned u = __builtin_bit_cast(unsigned, f);
    unsigned r = u + 0x7FFFu + ((u >> 16) & 1u);   // RNE
    return (unsigned short)(r >> 16);
}
__device__ __forceinline__ float bf2f(unsigned short b) {
    return __builtin_bit_cast(float, ((unsigned)b) << 16);
}

// ---------------- deg[t][i] = sum_j x[i][t][j] + 1e-8 ----------------
__global__ __launch_bounds__(256) void deg_kernel(const float* __restrict__ x,
                                                  float* __restrict__ deg) {
    const int i = blockIdx.x;
    const int t = blockIdx.y;
    const int tid = threadIdx.x;
    const float4* r4 = (const float4*)(x + ((size_t)i * TT + t) * NN);
    float4 a = r4[tid];
    float4 b = r4[tid + 256];
    float s = a.x + a.y + a.z + a.w + b.x + b.y + b.z + b.w;
    #pragma unroll
    for (int m = 32; m >= 1; m >>= 1) s += __shfl_xor(s, m, 64);
    __shared__ float red[4];
    if ((tid & 63) == 0) red[tid >> 6] = s;
    __syncthreads();
    if (tid == 0) deg[(size_t)t * NN + i] = red[0] + red[1] + red[2] + red[3] + 1e-8f;
}

// ---- GnT[tl][n][k] = bf16(Gn[k][n]) AND P1[tl][k][n] = bf16(w0*Gn + (1-w0)I) ----
__global__ __launch_bounds__(256) void gnt_init_kernel(const float* __restrict__ x,
                                                       const float* __restrict__ deg,
                                                       const float* __restrict__ w,
                                                       unsigned short* __restrict__ gnt,
                                                       unsigned short* __restrict__ p1,
                                                       int t0) {
    const int tl = blockIdx.z;
    const int t  = t0 + tl;
    float w0 = w[t * KST + 0];
    w0 = fminf(fmaxf(w0, 0.0f), 1.0f);
    const float om = 1.0f - w0;
    const int n0 = blockIdx.x * 64;
    const int k0 = blockIdx.y * 64;
    __shared__ float tile[64][65];
    const int tx = threadIdx.x & 63;
    const int ty = threadIdx.x >> 6;
    unsigned short* p1dst = p1 + (size_t)tl * NN * NN;
    #pragma unroll
    for (int p = 0; p < 16; ++p) {
        int kr = p * 4 + ty;
        float rd = 1.0f / deg[(size_t)t * NN + k0 + kr];
        float v = x[(((size_t)(k0 + kr)) * TT + t) * NN + n0 + tx] * rd;
        tile[kr][tx] = v;
        float pv = w0 * v + ((k0 + kr) == (n0 + tx) ? om : 0.0f);
        p1dst[(size_t)(k0 + kr) * NN + n0 + tx] = f2bf_bits(pv);
    }
    __syncthreads();
    unsigned short* dst = gnt + (size_t)tl * NN * NN;
    #pragma unroll
    for (int p = 0; p < 16; ++p) {
        int nr = p * 4 + ty;
        dst[(size_t)(n0 + nr) * NN + k0 + tx] = f2bf_bits(tile[tx][nr]);
    }
}

// ==========================================================================
// 256x256 tile, BK=64, 8 waves (2M x 4N), 128KB double-buffered LDS.
// R3 schedule = R1's 4-phase / 2-barrier-per-phase lockstep (best measured)
// with two isolated fixes:
//  (a) stage distribution {A0,B0}@P0, {B1}@P1, {A1}@P2, none@P3 and gates
//      vmcnt(4)/(6)/(6)/none -> every half's issue-to-gate distance is a
//      uniform 4 phases (~700-800cy) instead of R1's 3 (~550cy < HBM lat).
//  (b) bf0/bf1 retained in regs across the tile -> P3's LDS re-read gone.
// Steady-state per-wave ledger (8 outstanding at each P0 head):
//   P0: drain 4 (A0,B0) ; issue 4 -> 8
//   P1: drain 2 (B1)    ; issue 2 -> 8
//   P2: drain 2 (A1)    ; issue 2 -> 8
//   P3: reg-only MFMA, no gate, no stage
// WAR: every LDS half staged at phase P was last ds_read >=3 barriers
// earlier by all waves (reads complete pre-barrier via lgkm before MFMA).
// ==========================================================================
#define FENCE __asm__ volatile("" ::: "memory")

#define MFMA_PHASE(PA, PB, BARR)                                                  \
  do {                                                                            \
    _Pragma("unroll")                                                             \
    for (int f_ = 0; f_ < 4; ++f_) {                                              \
      _Pragma("unroll")                                                           \
      for (int g_ = 0; g_ < 2; ++g_) {                                            \
        acc[(PA)*4 + f_][(PB)*2 + g_] = __builtin_amdgcn_mfma_f32_16x16x32_bf16(  \
            af[f_][0], BARR[g_][0], acc[(PA)*4 + f_][(PB)*2 + g_], 0, 0, 0);      \
        acc[(PA)*4 + f_][(PB)*2 + g_] = __builtin_amdgcn_mfma_f32_16x16x32_bf16(  \
            af[f_][1], BARR[g_][1], acc[(PA)*4 + f_][(PB)*2 + g_], 0, 0, 0);      \
      }                                                                           \
    }                                                                             \
  } while (0)

__global__ __launch_bounds__(512, 2) void gemm_step256(
        const unsigned short* __restrict__ Pprev,
        const unsigned short* __restrict__ gnt,
        const float* __restrict__ w,
        unsigned short* __restrict__ Pnext,
        int t0, int kstep) {
    extern __shared__ char smem[];

    // bijective XCD swizzle (m204) + 2x2 supertiles (4MB strip set per XCD L2)
    const int nwg  = (int)gridDim.x;
    const int flat = (int)blockIdx.x;
    const int xcd  = flat & 7;
    const int q    = nwg >> 3, r = nwg & 7;
    const int wgid = (xcd < r ? xcd * (q + 1) : r * (q + 1) + (xcd - r) * q) + (flat >> 3);
    const int tl   = wgid >> 6;            // 64 tiles per time-slice
    const int s    = wgid & 63;
    const int g4   = s >> 2, w4 = s & 3;
    const int tm   = ((g4 >> 2) << 1) | (w4 >> 1);
    const int tn   = ((g4 & 3) << 1) | (w4 & 1);
    const int t    = t0 + tl;

    const int tid  = threadIdx.x;
    const int lane = tid & 63;
    const int wv   = tid >> 6;        // 0..7
    const int wm   = wv >> 2;         // 0..1 (M split)
    const int wn   = wv & 3;          // 0..3 (N split)
    const int lr   = lane & 15;
    const int quad = lane >> 4;
    const int swz  = lr & 7;          // read-side row swizzle key

    const unsigned short* Ab = Pprev + (size_t)tl * NN * NN;
    const unsigned short* Bb = gnt   + (size_t)tl * NN * NN;

    // --- staging source addresses (pre-swizzled k-slot, rule 21) ---
    const int srow  = lane >> 3;               // row low bits within 8-row stripe
    const int sslot = (lane & 7) ^ srow;       // inverse-swizzled 16B k-slot
    const unsigned short* pa[2][2];
    const unsigned short* pb[2][2];
    #pragma unroll
    for (int h = 0; h < 2; ++h)
        #pragma unroll
        for (int l = 0; l < 2; ++l) {
            const int rA = tm * 256 + h * 128 + l * 64 + wv * 8 + srow;
            const int rB = tn * 256 + h * 128 + l * 64 + wv * 8 + srow;
            pa[h][l] = Ab + (size_t)rA * NN + sslot * 8;
            pb[h][l] = Bb + (size_t)rB * NN + sslot * 8;
        }

    // LDS map: A half h of buf b at b*65536 + h*16384 ; B at +32768.
    // half = [128 rows][64 k] bf16, 128B rows, linear (global_load_lds dest).
    auto stageA = [&](int kt, int b, int h) {
        #pragma unroll
        for (int l = 0; l < 2; ++l)
            __builtin_amdgcn_global_load_lds(
                (as1_const_void*)(pa[h][l] + kt * BK),
                (as3_void*)(smem + b * 65536 + h * 16384 + l * 8192 + wv * 1024),
                16, 0, 0);
    };
    auto stageB = [&](int kt, int b, int h) {
        #pragma unroll
        for (int l = 0; l < 2; ++l)
            __builtin_amdgcn_global_load_lds(
                (as1_const_void*)(pb[h][l] + kt * BK),
                (as3_void*)(smem + b * 65536 + 32768 + h * 16384 + l * 8192 + wv * 1024),
                16, 0, 0);
    };

    // --- fragment loads (swizzled ds_read_b128, conflict-free) ---
    bf16x8 af[4][2];     // 4 m-frags x 2 k-slabs of current A-half
    bf16x8 bf0[2][2];    // B half0 frags (retained across the K-tile)
    bf16x8 bf1[2][2];    // B half1 frags
    const int sA = ((quad)     ^ swz) * 16;    // k-slab 0 slot byte
    const int sB = ((quad + 4) ^ swz) * 16;    // k-slab 1 slot byte
    auto lda = [&](int b, int half) {
        const char* base = smem + b * 65536 + half * 16384 + (wm * 64 + lr) * 128;
        #pragma unroll
        for (int f = 0; f < 4; ++f) {
            af[f][0] = *(const bf16x8*)(base + f * 2048 + sA);
            af[f][1] = *(const bf16x8*)(base + f * 2048 + sB);
        }
    };
    auto ldb = [&](int b, int half, bf16x8 (&dst)[2][2]) {
        const char* base = smem + b * 65536 + 32768 + half * 16384 + (wn * 32 + lr) * 128;
        #pragma unroll
        for (int g = 0; g < 2; ++g) {
            dst[g][0] = *(const bf16x8*)(base + g * 2048 + sA);
            dst[g][1] = *(const bf16x8*)(base + g * 2048 + sB);
        }
    };

    f32x4 acc[8][4];
    #pragma unroll
    for (int i = 0; i < 8; ++i)
        #pragma unroll
        for (int j = 0; j < 4; ++j)
            acc[i][j] = (f32x4){0.0f, 0.0f, 0.0f, 0.0f};

    // prologue: stage tile 0 into buf 0, oldest-first order A0,B0,B1,A1
    stageA(0, 0, 0);
    stageB(0, 0, 0);
    stageB(0, 0, 1);
    stageA(0, 0, 1);

    for (int kt = 0; kt < NKT2 - 1; ++kt) {
        const int buf  = kt & 1;
        const int nbuf = buf ^ 1;
        // P0: needs A0,B0 (oldest 4; issued @P0 of kt-1, 4 phases ago) -> vmcnt(4)
        FENCE; __builtin_amdgcn_s_waitcnt(0xF74); __builtin_amdgcn_s_barrier(); FENCE;
        lda(buf, 0);
        ldb(buf, 0, bf0);
        stageA(kt + 1, nbuf, 0);
        stageB(kt + 1, nbuf, 0);
        __builtin_amdgcn_s_setprio(1);
        MFMA_PHASE(0, 0, bf0);
        __builtin_amdgcn_s_setprio(0);
        FENCE; __builtin_amdgcn_s_barrier(); FENCE;
        // P1: needs B1 (issued @P1 of kt-1, 4 phases ago) -> vmcnt(6)
        FENCE; __builtin_amdgcn_s_waitcnt(0xF76); __builtin_amdgcn_s_barrier(); FENCE;
        ldb(buf, 1, bf1);
        stageB(kt + 1, nbuf, 1);
        __builtin_amdgcn_s_setprio(1);
        MFMA_PHASE(0, 1, bf1);
        __builtin_amdgcn_s_setprio(0);
        FENCE; __builtin_amdgcn_s_barrier(); FENCE;
        // P2: needs A1 (issued @P2 of kt-1, 4 phases ago) -> vmcnt(6)
        FENCE; __builtin_amdgcn_s_waitcnt(0xF76); __builtin_amdgcn_s_barrier(); FENCE;
        lda(buf, 1);
        stageA(kt + 1, nbuf, 1);
        __builtin_amdgcn_s_setprio(1);
        MFMA_PHASE(1, 1, bf1);
        __builtin_amdgcn_s_setprio(0);
        FENCE; __builtin_amdgcn_s_barrier(); FENCE;
        // P3: reg-only (af=A1, bf0 retained), no gate, no stage
        __builtin_amdgcn_s_barrier(); FENCE;
        __builtin_amdgcn_s_setprio(1);
        MFMA_PHASE(1, 0, bf0);
        __builtin_amdgcn_s_setprio(0);
        FENCE; __builtin_amdgcn_s_barrier(); FENCE;
    }

    {   // epilogue K-tile (no staging): gates tighten 4 -> 2 -> 0
        const int buf = (NKT2 - 1) & 1;
        FENCE; __builtin_amdgcn_s_waitcnt(0xF74); __builtin_amdgcn_s_barrier(); FENCE;
        lda(buf, 0);
        ldb(buf, 0, bf0);
        __builtin_amdgcn_s_setprio(1);
        MFMA_PHASE(0, 0, bf0);
        __builtin_amdgcn_s_setprio(0);
        FENCE; __builtin_amdgcn_s_waitcnt(0xF72); __builtin_amdgcn_s_barrier(); FENCE;
        ldb(buf, 1, bf1);
        __builtin_amdgcn_s_setprio(1);
        MFMA_PHASE(0, 1, bf1);
        __builtin_amdgcn_s_setprio(0);
        FENCE; __builtin_amdgcn_s_waitcnt(0xF70); __builtin_amdgcn_s_barrier(); FENCE;
        lda(buf, 1);
        __builtin_amdgcn_s_setprio(1);
        MFMA_PHASE(1, 1, bf1);
        MFMA_PHASE(1, 0, bf0);
        __builtin_amdgcn_s_setprio(0);
    }

    // epilogue: P_next = wk*acc + (1-wk)*I, bf16
    float wk = w[t * KST + kstep];
    wk = fminf(fmaxf(wk, 0.0f), 1.0f);
    const float om = 1.0f - wk;
    unsigned short* __restrict__ Pn = Pnext + (size_t)tl * NN * NN;
    #pragma unroll
    for (int F = 0; F < 8; ++F) {
        const int mrow0 = tm * 256 + (F >> 2) * 128 + wm * 64 + (F & 3) * 16 + quad * 4;
        #pragma unroll
        for (int v = 0; v < 4; ++v) {
            const int m = mrow0 + v;
            const size_t mb = (size_t)m * NN;
            #pragma unroll
            for (int G = 0; G < 4; ++G) {
                const int n = tn * 256 + (G >> 1) * 128 + wn * 32 + (G & 1) * 16 + lr;
                float val = wk * acc[F][G][v] + (m == n ? om : 0.0f);
                Pn[mb + n] = f2bf_bits(val);
            }
        }
    }
}

// ---- out[m][t][:] = LayerNorm( sum_k P_k[m][:] ), P_k bf16 ----
__global__ __launch_bounds__(256) void ln_kernel(const unsigned short* __restrict__ Pall,
                                                 const float* __restrict__ gamma,
                                                 const float* __restrict__ beta,
                                                 float* __restrict__ out,
                                                 int t0, size_t strideK) {
    const int m  = blockIdx.x;
    const int tl = blockIdx.y;
    const int t  = t0 + tl;
    const int tid = threadIdx.x;
    const int j = tid * 8;

    const size_t rbase = (size_t)tl * NN * NN + (size_t)m * NN + j;
    float v[8] = {0, 0, 0, 0, 0, 0, 0, 0};
    #pragma unroll
    for (int k = 0; k < KST; ++k) {
        u16x8 pv = *(const u16x8*)(Pall + (size_t)k * strideK + rbase);
        #pragma unroll
        for (int e = 0; e < 8; ++e) v[e] += bf2f(pv[e]);
    }

    float s = 0.0f;
    #pragma unroll
    for (int e = 0; e < 8; ++e) s += v[e];
    #pragma unroll
    for (int mm = 32; mm >= 1; mm >>= 1) s += __shfl_xor(s, mm, 64);
    __shared__ float red[4];
    if ((tid & 63) == 0) red[tid >> 6] = s;
    __syncthreads();
    const float mu = (red[0] + red[1] + red[2] + red[3]) * (1.0f / NN);

    float q = 0.0f;
    float dx[8];
    #pragma unroll
    for (int e = 0; e < 8; ++e) { dx[e] = v[e] - mu; q += dx[e] * dx[e]; }
    __syncthreads();
    #pragma unroll
    for (int mm = 32; mm >= 1; mm >>= 1) q += __shfl_xor(q, mm, 64);
    if ((tid & 63) == 0) red[tid >> 6] = q;
    __syncthreads();
    const float var = (red[0] + red[1] + red[2] + red[3]) * (1.0f / NN);
    const float sc = rsqrtf(var + 1e-5f);

    float4 g0 = *(const float4*)(gamma + j);
    float4 g1 = *(const float4*)(gamma + j + 4);
    float4 b0 = *(const float4*)(beta + j);
    float4 b1 = *(const float4*)(beta + j + 4);
    const size_t ob = ((size_t)m * TT + t) * NN + j;
    float4 o0, o1;
    o0.x = dx[0] * sc * g0.x + b0.x;  o0.y = dx[1] * sc * g0.y + b0.y;
    o0.z = dx[2] * sc * g0.z + b0.z;  o0.w = dx[3] * sc * g0.w + b0.w;
    o1.x = dx[4] * sc * g1.x + b1.x;  o1.y = dx[5] * sc * g1.y + b1.y;
    o1.z = dx[6] * sc * g1.z + b1.z;  o1.w = dx[7] * sc * g1.w + b1.w;
    *(float4*)(out + ob)     = o0;
    *(float4*)(out + ob + 4) = o1;
}

extern "C" void kernel_launch(void* const* d_in, const int* in_sizes, int n_in,
                              void* d_out, int out_size, void* d_ws, size_t ws_size,
                              hipStream_t stream) {
    (void)in_sizes; (void)n_in; (void)out_size;
    const float* x     = (const float*)d_in[0];
    const float* w     = (const float*)d_in[1];
    const float* gamma = (const float*)d_in[2];
    const float* beta  = (const float*)d_in[3];
    float* out = (float*)d_out;

    static bool attr_done = false;
    if (!attr_done) {
        (void)hipFuncSetAttribute((const void*)gemm_step256,
                                  hipFuncAttributeMaxDynamicSharedMemorySize, 131072);
        attr_done = true;
    }

    char* ws = (char*)d_ws;
    float* deg = (float*)ws;
    size_t off = ((size_t)TT * NN * sizeof(float) + 255) & ~(size_t)255;
    const size_t per_t = (size_t)NN * NN * sizeof(unsigned short);   // 8 MB
    size_t avail = ws_size > off ? ws_size - off : 0;
    int TB = (int)(avail / ((1 + KST) * per_t));
    if (TB < 1) TB = 1;
    if (TB > TT) TB = TT;
    unsigned short* gnt  = (unsigned short*)(ws + off);
    unsigned short* Pall = gnt + (size_t)TB * NN * NN;
    const size_t strideK = (size_t)TB * NN * NN;

    deg_kernel<<<dim3(NN, TT), 256, 0, stream>>>(x, deg);

    for (int t0 = 0; t0 < TT; t0 += TB) {
        const int tb = (TT - t0) < TB ? (TT - t0) : TB;
        gnt_init_kernel<<<dim3(32, 32, tb), 256, 0, stream>>>(x, deg, w, gnt, Pall, t0);
        for (int k = 2; k <= KST; ++k) {
            const unsigned short* Pp = Pall + (size_t)(k - 2) * strideK;
            unsigned short*       Pn = Pall + (size_t)(k - 1) * strideK;
            gemm_step256<<<dim3(64 * tb), 512, 131072, stream>>>(Pp, gnt, w, Pn, t0, k - 1);
        }
        ln_kernel<<<dim3(NN, tb), 256, 0, stream>>>(Pall, gamma, beta, out, t0, strideK);
    }
}